// Round 1
// baseline (397.947 us; speedup 1.0000x reference)
//
#include <hip/hip_runtime.h>
#include <math.h>

#define HD 128
#define NNODE 8192
#define KNBR 8
#define NHS ((size_t)NNODE*(size_t)HD)

#define EPSF 1e-6f
#define PMX 0.9999f
#define ATHC (1.0f-1e-5f)
#define TANC 1.47079f

static __device__ __forceinline__ float wred(float v){
#pragma unroll
  for(int m=32;m;m>>=1) v += __shfl_xor(v,m,64);
  return v;
}
static __device__ __forceinline__ float hred(float v){
#pragma unroll
  for(int m=16;m;m>>=1) v += __shfl_xor(v,m,64);
  return v;
}
static __device__ __forceinline__ float atanh_c(float x){
  x = fminf(fmaxf(x,-ATHC),ATHC);
  return atanhf(x);
}
static __device__ __forceinline__ float tan_c(float x){
  x = fminf(fmaxf(x,-TANC),TANC);
  return tanf(x);
}
static __device__ __forceinline__ float sigm(float x){ return 1.0f/(1.0f+expf(-x)); }
static __device__ __forceinline__ float safeden(float d){
  return d>=0.0f ? fmaxf(d,EPSF) : fminf(d,-EPSF);
}

// ---------------- workspace layout (units of NHS floats) ----------------
// 0..5  : XPre1, XPre2, LH1, LH2, LC1, LC2        (dead after GEMM-A)
// 6..11 : S1,S2,S3,F1,F2,F3                        (dead after phaseB)
// 12..14: CS1,CS2,CS3                              (dead after phaseB)
// 15..17: XP,XS,XE
// 18..20: H1P,H1S,H1E
// 21..23: V1,V2,V3
// 24..26: LP,LS,LE
// 27..29: c_1,c_2,c_3
// YP/YS/YE overlay 0..8 (3*NHS each region of 384-wide rows)
// scalars at 30*NHS: y2p(+0), y2s(+8192), d1(+16384), d2(+24576), c1n2(+32768), c2n2(+40960)

// ---------------- kernel 1: per-row pre-transforms ----------------
__global__ __launch_bounds__(256) void k_pre(
    const float* __restrict__ x, const float* __restrict__ h1,
    const float* __restrict__ h2, const float* __restrict__ c1,
    const float* __restrict__ c2, float* __restrict__ ws)
{
  float* XP1 = ws + 0*NHS; float* XP2 = ws + 1*NHS;
  float* LH1 = ws + 2*NHS; float* LH2 = ws + 3*NHS;
  float* LC1 = ws + 4*NHS; float* LC2 = ws + 5*NHS;
  int row = blockIdx.x*4 + (threadIdx.x>>6);
  int l = threadIdx.x & 63;
  size_t i0 = (size_t)row*HD + l, i1 = i0 + 64;
  float xa=x[i0], xb=x[i1];
  float h1a=h1[i0], h1b=h1[i1];
  float h2a=h2[i0], h2b=h2[i1];
  float c1a=c1[i0], c1b=c1[i1];
  float c2a=c2[i0], c2b=c2[i1];
  float xsq = wred(xa*xa+xb*xb);
  float h1sq = wred(h1a*h1a+h1b*h1b);
  float h2sq = wred(h2a*h2a+h2b*h2b);
  float c1sq = wred(c1a*c1a+c1b*c1b);
  float c2sq = wred(c2a*c2a+c2b*c2b);
  float nx = sqrtf(xsq+1e-15f);
  { // logmap0(expmap0(x,KP),KP)
    float t = tanhf(nx);
    float f = fminf(t,PMX)/nx;
    float ny = sqrtf(f*f*xsq + 1e-15f);
    float g = atanh_c(ny)/ny * f;
    XP1[i0]=g*xa; XP1[i1]=g*xb;
  }
  { // logmap0(expmap0(x,KS),KS)
    float t = tan_c(nx);
    float f = t/nx;
    float ny = sqrtf(f*f*xsq + 1e-15f);
    float g = atanf(ny)/ny * f;
    XP2[i0]=g*xa; XP2[i1]=g*xb;
  }
  { float n=sqrtf(h1sq+1e-15f); float g=atanh_c(n)/n; LH1[i0]=g*h1a; LH1[i1]=g*h1b; }
  { float n=sqrtf(h2sq+1e-15f); float g=atanf(n)/n;   LH2[i0]=g*h2a; LH2[i1]=g*h2b; }
  { float n=sqrtf(c1sq+1e-15f); float g=atanh_c(n)/n; LC1[i0]=g*c1a; LC1[i1]=g*c1b; }
  { float n=sqrtf(c2sq+1e-15f); float g=atanf(n)/n;   LC2[i0]=g*c2a; LC2[i1]=g*c2b; }
}

// ---------------- generic tiled f32 GEMM: out = post(in @ W^T + b) ----------------
enum { P_ID=0, P_EXP_P, P_EXP_S, P_SIG, P_TANH, P_SIG_LOG_P, P_SIG_LOG_S,
       P_LOGSIG_P, P_LOGSIG_S, P_TANH_EXP_P, P_TANH_EXP_S };

struct Job { const float* in; const float* W; const float* b; float* out;
             int col0; int pitch; int post; };
struct JobTab { Job j[12]; };

__global__ __launch_bounds__(256) void k_gemm(JobTab tab){
  Job jb = tab.j[blockIdx.y];
  __shared__ float Wt[64*128];   // K-half of W, transposed + XOR swizzled
  __shared__ float Un[32*132];   // 32 input rows, padded pitch
  const int t = threadIdx.x;
  const int r0 = blockIdx.x*32;
#pragma unroll
  for(int rep=0;rep<4;rep++){
    int idx = t + 256*rep;
    int r = idx>>5, i4 = (idx&31)<<2;
    const float4 v = *(const float4*)(jb.in + (size_t)(r0+r)*HD + i4);
    *(float4*)&Un[r*132 + i4] = v;
  }
  float acc[4][4];
#pragma unroll
  for(int a=0;a<4;a++)
#pragma unroll
    for(int b=0;b<4;b++) acc[a][b]=0.0f;
  const int oo = t&31, gg = t>>5;
  const int o4 = oo*4, r4 = gg*4;
  const float* Wb = jb.W + (size_t)jb.col0*HD;
  for(int h=0;h<2;h++){
    __syncthreads();
#pragma unroll
    for(int rep=0;rep<8;rep++){
      int idx = t + 256*rep;
      int i4q = idx&15, o = idx>>4;
      int il = i4q*4;
      const float4 v = *(const float4*)(Wb + (size_t)o*HD + 64*h + il);
      int oc = o ^ ((i4q&7)<<2);
      Wt[(il+0)*128 + oc] = v.x;
      Wt[(il+1)*128 + oc] = v.y;
      Wt[(il+2)*128 + oc] = v.z;
      Wt[(il+3)*128 + oc] = v.w;
    }
    __syncthreads();
    const int ib = 64*h;
#pragma unroll 8
    for(int i=0;i<64;i++){
      const float4 wv = *(const float4*)&Wt[i*128 + (o4 ^ (((i>>2)&7)<<2))];
      float u0 = Un[(r4+0)*132 + ib+i];
      float u1 = Un[(r4+1)*132 + ib+i];
      float u2 = Un[(r4+2)*132 + ib+i];
      float u3 = Un[(r4+3)*132 + ib+i];
      acc[0][0]+=u0*wv.x; acc[0][1]+=u0*wv.y; acc[0][2]+=u0*wv.z; acc[0][3]+=u0*wv.w;
      acc[1][0]+=u1*wv.x; acc[1][1]+=u1*wv.y; acc[1][2]+=u1*wv.z; acc[1][3]+=u1*wv.w;
      acc[2][0]+=u2*wv.x; acc[2][1]+=u2*wv.y; acc[2][2]+=u2*wv.z; acc[2][3]+=u2*wv.w;
      acc[3][0]+=u3*wv.x; acc[3][1]+=u3*wv.y; acc[3][2]+=u3*wv.z; acc[3][3]+=u3*wv.w;
    }
  }
  float bar[4];
  { const float4 bv = *(const float4*)(jb.b + jb.col0 + o4);
    bar[0]=bv.x; bar[1]=bv.y; bar[2]=bv.z; bar[3]=bv.w; }
  float v[4][4];
#pragma unroll
  for(int a=0;a<4;a++)
#pragma unroll
    for(int b=0;b<4;b++) v[a][b] = acc[a][b] + bar[b];
  float nraw[4];
#pragma unroll
  for(int a=0;a<4;a++){
    float s = v[a][0]*v[a][0]+v[a][1]*v[a][1]+v[a][2]*v[a][2]+v[a][3]*v[a][3];
    nraw[a] = hred(s);
  }
  switch(jb.post){
    case P_ID: break;
    case P_EXP_P:
#pragma unroll
      for(int a=0;a<4;a++){
        float n=sqrtf(nraw[a]+1e-15f); float tt=tanhf(n); float f=fminf(tt,PMX)/n;
        for(int b=0;b<4;b++) v[a][b]*=f;
      } break;
    case P_EXP_S:
#pragma unroll
      for(int a=0;a<4;a++){
        float n=sqrtf(nraw[a]+1e-15f); float f=tan_c(n)/n;
        for(int b=0;b<4;b++) v[a][b]*=f;
      } break;
    case P_SIG:
#pragma unroll
      for(int a=0;a<4;a++) for(int b=0;b<4;b++) v[a][b]=sigm(v[a][b]);
      break;
    case P_TANH:
#pragma unroll
      for(int a=0;a<4;a++) for(int b=0;b<4;b++) v[a][b]=tanhf(v[a][b]);
      break;
    case P_SIG_LOG_P:
#pragma unroll
      for(int a=0;a<4;a++){
        float n=sqrtf(nraw[a]+1e-15f); float tt=tanhf(n); float f=fminf(tt,PMX)/n;
        float z[4];
        for(int b=0;b<4;b++) z[b]=sigm(f*v[a][b]);
        float zr=hred(z[0]*z[0]+z[1]*z[1]+z[2]*z[2]+z[3]*z[3]);
        float zn=sqrtf(zr+1e-15f);
        float g=atanh_c(zn)/zn;
        for(int b=0;b<4;b++) v[a][b]=g*z[b];
      } break;
    case P_SIG_LOG_S:
#pragma unroll
      for(int a=0;a<4;a++){
        float n=sqrtf(nraw[a]+1e-15f); float f=tan_c(n)/n;
        float z[4];
        for(int b=0;b<4;b++) z[b]=sigm(f*v[a][b]);
        float zr=hred(z[0]*z[0]+z[1]*z[1]+z[2]*z[2]+z[3]*z[3]);
        float zn=sqrtf(zr+1e-15f);
        float g=atanf(zn)/zn;
        for(int b=0;b<4;b++) v[a][b]=g*z[b];
      } break;
    case P_LOGSIG_P:
#pragma unroll
      for(int a=0;a<4;a++){
        float n=sqrtf(nraw[a]+1e-15f); float tt=tanhf(n); float f=fminf(tt,PMX)/n;
        float ny=sqrtf(f*f*nraw[a]+1e-15f);
        float g=atanh_c(ny)/ny*f;
        for(int b=0;b<4;b++) v[a][b]=sigm(g*v[a][b]);
      } break;
    case P_LOGSIG_S:
#pragma unroll
      for(int a=0;a<4;a++){
        float n=sqrtf(nraw[a]+1e-15f); float f=tan_c(n)/n;
        float ny=sqrtf(f*f*nraw[a]+1e-15f);
        float g=atanf(ny)/ny*f;
        for(int b=0;b<4;b++) v[a][b]=sigm(g*v[a][b]);
      } break;
    case P_TANH_EXP_P:
#pragma unroll
      for(int a=0;a<4;a++){
        float n=sqrtf(nraw[a]+1e-15f); float tt=tanhf(n); float f=fminf(tt,PMX)/n;
        float ny=sqrtf(f*f*nraw[a]+1e-15f);
        float g=atanh_c(ny)/ny*f;
        float T[4];
        for(int b=0;b<4;b++) T[b]=tanhf(g*v[a][b]);
        float Tr=hred(T[0]*T[0]+T[1]*T[1]+T[2]*T[2]+T[3]*T[3]);
        float Tn=sqrtf(Tr+1e-15f);
        float t2=tanhf(Tn); float f2=fminf(t2,PMX)/Tn;
        for(int b=0;b<4;b++) v[a][b]=f2*T[b];
      } break;
    case P_TANH_EXP_S:
#pragma unroll
      for(int a=0;a<4;a++){
        float n=sqrtf(nraw[a]+1e-15f); float f=tan_c(n)/n;
        float ny=sqrtf(f*f*nraw[a]+1e-15f);
        float g=atanf(ny)/ny*f;
        float T[4];
        for(int b=0;b<4;b++) T[b]=tanhf(g*v[a][b]);
        float Tr=hred(T[0]*T[0]+T[1]*T[1]+T[2]*T[2]+T[3]*T[3]);
        float Tn=sqrtf(Tr+1e-15f);
        float f2=tan_c(Tn)/Tn;
        for(int b=0;b<4;b++) v[a][b]=f2*T[b];
      } break;
  }
#pragma unroll
  for(int a=0;a<4;a++){
    float4 ov = make_float4(v[a][0],v[a][1],v[a][2],v[a][3]);
    *(float4*)(jb.out + (size_t)(r0+r4+a)*jb.pitch + jb.col0 + o4) = ov;
  }
}

// ---------------- kernel 3: per-unique-node elementwise (phase B) ----------------
__global__ __launch_bounds__(256) void k_phaseB(
  const float* __restrict__ h1,const float* __restrict__ h2,const float* __restrict__ h3,
  const float* __restrict__ c1,const float* __restrict__ c2,const float* __restrict__ c3,
  const float* __restrict__ del_t, const float* __restrict__ dsc,
  float* __restrict__ ws)
{
  const float* S1 = ws+6*NHS;  const float* S2 = ws+7*NHS;  const float* S3 = ws+8*NHS;
  const float* F1 = ws+9*NHS;  const float* F2 = ws+10*NHS; const float* F3 = ws+11*NHS;
  const float* Q1 = ws+12*NHS; const float* Q2 = ws+13*NHS; const float* Q3 = ws+14*NHS;
  float* H1P = ws+18*NHS; float* H1S = ws+19*NHS; float* H1E = ws+20*NHS;
  float* V1 = ws+21*NHS;  float* V2 = ws+22*NHS;  float* V3 = ws+23*NHS;
  float* y2p = ws+30*NHS; float* y2s = y2p+8192; float* d1 = y2p+16384; float* d2 = y2p+24576;

  int j = blockIdx.x*4 + (threadIdx.x>>6);
  int l = threadIdx.x&63;
  size_t i0 = (size_t)j*HD+l, i1 = i0+64;
  float h1a=h1[i0],h1b=h1[i1], h2a=h2[i0],h2b=h2[i1], h3a=h3[i0],h3b=h3[i1];
  float c1a=c1[i0],c1b=c1[i1], c2a=c2[i0],c2b=c2[i1], c3a=c3[i0],c3b=c3[i1];
  float s1a=S1[i0],s1b=S1[i1], s2a=S2[i0],s2b=S2[i1], s3a=S3[i0],s3b=S3[i1];
  float f1a=F1[i0],f1b=F1[i1], f2a=F2[i0],f2b=F2[i1], f3a=F3[i0],f3b=F3[i1];
  float q1a=Q1[i0],q1b=Q1[i1], q2a=Q2[i0],q2b=Q2[i1], q3a=Q3[i0],q3b=Q3[i1];
  float g = dsc[0]/(del_t[j]+1.0f);

  float h1sq = wred(h1a*h1a+h1b*h1b); float n1 = sqrtf(h1sq+1e-15f);
  float h2sq = wred(h2a*h2a+h2b*h2b); float n2 = sqrtf(h2sq+1e-15f);
  float h3sq = wred(h3a*h3a+h3b*h3b); float n3 = sqrtf(h3sq+1e-15f);
  float w1a=s1a*h1a, w1b=s1b*h1b;
  float w2a=s2a*h2a, w2b=s2b*h2b;
  float w3a=s3a*h3a, w3b=s3b*h3b;
  float w1sq = wred(w1a*w1a+w1b*w1b); float nw1 = sqrtf(w1sq+1e-15f);
  float w2sq = wred(w2a*w2a+w2b*w2b); float nw2 = sqrtf(w2sq+1e-15f);
  float w3sq = wred(w3a*w3a+w3b*w3b); float nw3 = sqrtf(w3sq+1e-15f);

  // ---- h_1p (Poincare stack wmid)
  float t1 = tanhf(nw1/n1 * atanh_c(n1));
  float fp1 = fminf(t1,PMX)/nw1; float np1 = fminf(t1,PMX);
  float nu2 = atanf(n2);
  float ne2 = fminf(tanhf(nu2),PMX);
  float t2 = tanhf(nw2/n2 * atanh_c(ne2));
  float fp2 = fminf(t2,PMX)/nw2; float np2 = fminf(t2,PMX);
  float ne3 = fminf(tanhf(n3),PMX);
  float t3 = tanhf(nw3/n3 * atanh_c(ne3));
  float fp3 = fminf(t3,PMX)/nw3; float np3 = fminf(t3,PMX);
  {
    float lamA = 2.0f/(1.0f-np1*np1), lamB = 2.0f/(1.0f-np2*np2), lamC = 2.0f/(1.0f-np3*np3);
    float dn = fmaxf(fabsf(lamA+lamB+lamC-3.0f), EPSF);
    float va = (lamA*fp1*w1a + lamB*fp2*w2a + lamC*fp3*w3a)/dn;
    float vb = (lamA*fp1*w1b + lamB*fp2*w2b + lamC*fp3*w3b)/dn;
    float vsq = wred(va*va+vb*vb); float nv = sqrtf(vsq+1e-15f);
    float tt = tanhf(0.5f*atanh_c(nv)); float ff = 3.0f*fminf(tt,PMX)/nv;
    H1P[i0]=ff*va; H1P[i1]=ff*vb;
    if(l==0) y2p[j] = ff*ff*vsq;
  }
  // ---- h_1s
  float t2s, fs2;
  {
    float nx1s = tan_c(atanh_c(n1));
    float t1s = tanhf(nw1/n1 * atanh_c(nx1s));
    float fs1 = fminf(t1s,PMX)/nw1; float ns1 = fminf(t1s,PMX);
    t2s = tan_c(nw2/n2 * atanf(n2));
    fs2 = t2s/nw2;
    float nx3s = tan_c(n3);
    float t3s = tan_c(nw3/n3 * atanf(nx3s));
    float fs3 = t3s/nw3;
    float lA = 2.0f/(1.0f-ns1*ns1), lB = 2.0f/(1.0f-t2s*t2s), lC = 2.0f/(1.0f-t3s*t3s);
    float dns = fmaxf(fabsf(lA+lB+lC-3.0f), EPSF);
    float vsa = (lA*fs1*w1a + lB*fs2*w2a + lC*fs3*w3a)/dns;
    float vsb = (lA*fs1*w1b + lB*fs2*w2b + lC*fs3*w3b)/dns;
    float vssq = wred(vsa*vsa+vsb*vsb); float nvs = sqrtf(vssq+1e-15f);
    float tts = tan_c(0.5f*atanf(nvs)); float ffs = 3.0f*tts/nvs;
    H1S[i0]=ffs*vsa; H1S[i1]=ffs*vsb;
    if(l==0) y2s[j] = ffs*ffs*vssq;
  }
  // ---- h_1e
  {
    float ne1 = sqrtf(fp1*fp1*w1sq + 1e-15f);
    float ge1 = atanh_c(ne1)/ne1;
    float n2s_ = sqrtf(fs2*fs2*w2sq + 1e-15f);
    float ge2 = atanf(n2s_)/n2s_;
    H1E[i0] = ge1*fp1*w1a + ge2*fs2*w2a + s3a*h3a;
    H1E[i1] = ge1*fp1*w1b + ge2*fs2*w2b + s3b*h3b;
  }
  float ng = sqrtf(g*g+1e-15f);
  // ---- Poincare cell: V1 = lam*pwmul(f_p, ckt_p, KP), d1 = lam-1
  {
    float q1sq = wred(q1a*q1a+q1b*q1b);
    float c1rs = wred(c1a*c1a+c1b*c1b);
    float dq1 = wred(q1a*c1a+q1b*c1b);
    float xy = -dq1;
    float aa = 1.0f+2.0f*xy+c1rs, bb = 1.0f-q1sq;
    float dd = safeden(1.0f+2.0f*xy+q1sq*c1rs);
    float m1a = (aa*(-q1a)+bb*c1a)/dd, m1b = (aa*(-q1b)+bb*c1b)/dd;
    float m1sq = (aa*aa*q1sq + 2.0f*aa*bb*xy + bb*bb*c1rs)/(dd*dd);
    float mdq = (-aa*q1sq + bb*dq1)/dd;
    { float nm = sqrtf(m1sq+1e-15f);
      if(nm>PMX){ float sc=PMX/nm; m1a*=sc; m1b*=sc; m1sq*=sc*sc; mdq*=sc; } }
    float nwg = sqrtf(g*g*q1sq+1e-15f);
    float tg = tanhf(nwg/ng * atanh_c(ng));
    float fX = fminf(tg,PMX)/nwg * g;
    float X2sq = fX*fX*q1sq;
    float xy2 = fX*mdq;
    float a2 = 1.0f+2.0f*xy2+X2sq, b2 = 1.0f-m1sq;
    float d2d = safeden(1.0f+2.0f*xy2+m1sq*X2sq);
    float ka = (a2*m1a + b2*fX*q1a)/d2d, kb = (a2*m1b + b2*fX*q1b)/d2d;
    float ksq = (a2*a2*m1sq + 2.0f*a2*b2*xy2 + b2*b2*X2sq)/(d2d*d2d);
    { float nk0 = sqrtf(ksq+1e-15f);
      if(nk0>PMX){ float sc=PMX/nk0; ka*=sc; kb*=sc; ksq*=sc*sc; } }
    float nk = sqrtf(ksq+1e-15f);
    float wfa = f1a*ka, wfb = f1b*kb;
    float wfsq = wred(wfa*wfa+wfb*wfb); float nwf = sqrtf(wfsq+1e-15f);
    float tu = tanhf(nwf/nk * atanh_c(nk));
    float fu = fminf(tu,PMX)/nwf;
    float u1sq = fu*fu*wfsq;
    float lam = 2.0f/(1.0f-u1sq);
    V1[i0]=lam*fu*wfa; V1[i1]=lam*fu*wfb;
    if(l==0) d1[j]=lam-1.0f;
  }
  // ---- Sphere cell
  {
    float q2sq = wred(q2a*q2a+q2b*q2b);
    float c2rs = wred(c2a*c2a+c2b*c2b);
    float dq2 = wred(q2a*c2a+q2b*c2b);
    float xy = -dq2;
    float aa = 1.0f-2.0f*xy-c2rs, bb = 1.0f+q2sq;
    float dd = safeden(1.0f-2.0f*xy+q2sq*c2rs);
    float ma = (aa*(-q2a)+bb*c2a)/dd, mb = (aa*(-q2b)+bb*c2b)/dd;
    float msq = (aa*aa*q2sq + 2.0f*aa*bb*xy + bb*bb*c2rs)/(dd*dd);
    float mdq = (-aa*q2sq + bb*dq2)/dd;
    float nwg = sqrtf(g*g*q2sq+1e-15f);
    float tg = tan_c(nwg/ng * atanf(ng));
    float fX = tg/nwg * g;
    float X2sq = fX*fX*q2sq;
    float xy2 = fX*mdq;
    float a2 = 1.0f-2.0f*xy2-X2sq, b2 = 1.0f+msq;
    float d2d = safeden(1.0f-2.0f*xy2+msq*X2sq);
    float ka = (a2*ma + b2*fX*q2a)/d2d, kb = (a2*mb + b2*fX*q2b)/d2d;
    float ksq = (a2*a2*msq + 2.0f*a2*b2*xy2 + b2*b2*X2sq)/(d2d*d2d);
    float nk = sqrtf(ksq+1e-15f);
    float wfa = f2a*ka, wfb = f2b*kb;
    float wfsq = wred(wfa*wfa+wfb*wfb); float nwf = sqrtf(wfsq+1e-15f);
    float tu = tan_c(nwf/nk * atanf(nk));
    float fu = tu/nwf;
    float u2sq = fu*fu*wfsq;
    float lam = 2.0f/(1.0f+u2sq);
    V2[i0]=lam*fu*wfa; V2[i1]=lam*fu*wfb;
    if(l==0) d2[j]=lam-1.0f;
  }
  // ---- Euclid cell
  {
    float kea = c3a + q3a*(g-1.0f), keb = c3b + q3b*(g-1.0f);
    V3[i0]=f3a*kea; V3[i1]=f3b*keb;
  }
}

// ---------------- kernel 4: attention + K-reductions (phase C1) ----------------
__global__ __launch_bounds__(256) void k_attn(
  const int* __restrict__ nbr, float* __restrict__ ws)
{
  const float* XP = ws+15*NHS; const float* XS = ws+16*NHS; const float* XE = ws+17*NHS;
  const float* H1P = ws+18*NHS; const float* H1S = ws+19*NHS; const float* H1E = ws+20*NHS;
  const float* V1 = ws+21*NHS; const float* V2 = ws+22*NHS; const float* V3 = ws+23*NHS;
  float* LP = ws+24*NHS; float* LS = ws+25*NHS; float* LE = ws+26*NHS;
  float* C1o = ws+27*NHS; float* C2o = ws+28*NHS; float* C3o = ws+29*NHS;
  const float* y2p = ws+30*NHS; const float* y2s = y2p+8192;
  const float* d1 = y2p+16384; const float* d2 = y2p+24576;
  float* c1n2 = (float*)(y2p+32768); float* c2n2 = (float*)(y2p+40960);

  int n = blockIdx.x*4 + (threadIdx.x>>6);
  int l = threadIdx.x&63;
  size_t i0 = (size_t)n*HD+l, i1 = i0+64;
  float XPa=XP[i0], XPb=XP[i1];
  float XSa=XS[i0], XSb=XS[i1];
  float XEa=XE[i0], XEb=XE[i1];
  float x2p = wred(XPa*XPa+XPb*XPb);
  float x2s = wred(XSa*XSa+XSb*XSb);
  float HPa[8],HPb[8],HSa[8],HSb[8],HEa[8],HEb[8],y2pk[8],y2sk[8];
  float scp[8],scs[8],sce[8];
  float v1a=0,v1b=0,v2a=0,v2b=0,v3a=0,v3b=0,ds1=0,ds2=0;
  const float rs = 0.08838834764831845f; // 1/sqrt(128)
#pragma unroll
  for(int k=0;k<8;k++){
    int j = nbr[n*KNBR+k];
    size_t j0 = (size_t)j*HD+l, j1 = j0+64;
    HPa[k]=H1P[j0]; HPb[k]=H1P[j1];
    HSa[k]=H1S[j0]; HSb[k]=H1S[j1];
    HEa[k]=H1E[j0]; HEb[k]=H1E[j1];
    y2pk[k]=y2p[j]; y2sk[k]=y2s[j];
    v1a+=V1[j0]; v1b+=V1[j1];
    v2a+=V2[j0]; v2b+=V2[j1];
    v3a+=V3[j0]; v3b+=V3[j1];
    ds1+=d1[j]; ds2+=d2[j];
    float dp = wred(XPa*HPa[k]+XPb*HPb[k]);
    {
      float xy=-dp, y2=y2pk[k];
      float aa=1.0f+2.0f*xy+y2, bb=1.0f-x2p;
      float dd=safeden(1.0f+2.0f*xy+x2p*y2);
      float nsq=(aa*aa*x2p+2.0f*aa*bb*xy+bb*bb*y2)/(dd*dd);
      float nn=fminf(sqrtf(nsq+1e-15f),PMX);
      scp[k] = -2.0f*atanh_c(nn);
    }
    float dsv = wred(XSa*HSa[k]+XSb*HSb[k]);
    {
      float xy=-dsv, y2=y2sk[k];
      float aa=1.0f-2.0f*xy-y2, bb=1.0f+x2s;
      float dd=safeden(1.0f-2.0f*xy+x2s*y2);
      float nsq=(aa*aa*x2s+2.0f*aa*bb*xy+bb*bb*y2)/(dd*dd);
      float nn=sqrtf(nsq+1e-15f);
      scs[k] = -2.0f*atanf(nn);
    }
    sce[k] = wred(XEa*HEa[k]+XEb*HEb[k])*rs;
  }
  { // p attention + wmid
    float mx=scp[0];
#pragma unroll
    for(int k=1;k<8;k++) mx=fmaxf(mx,scp[k]);
    float a[8]; float s=0;
#pragma unroll
    for(int k=0;k<8;k++){ a[k]=expf(scp[k]-mx); s+=a[k]; }
    float inv=1.0f/s;
    float na=0,nb=0,de=0;
#pragma unroll
    for(int k=0;k<8;k++){
      float lam = 2.0f/(1.0f-y2pk[k]); float w=a[k]*inv;
      na+=w*lam*HPa[k]; nb+=w*lam*HPb[k]; de+=w*(lam-1.0f);
    }
    de = fmaxf(fabsf(de),EPSF);
    na/=de; nb/=de;
    float vsq=wred(na*na+nb*nb); float nv=sqrtf(vsq+1e-15f);
    float tt=tanhf(0.5f*atanh_c(nv)); float f=fminf(tt,PMX)/nv;
    float ha=f*na, hb=f*nb;
    float hn=sqrtf(f*f*vsq+1e-15f);
    float gl=atanh_c(hn)/hn;
    LP[i0]=gl*ha; LP[i1]=gl*hb;
  }
  { // s attention + wmid
    float mx=scs[0];
#pragma unroll
    for(int k=1;k<8;k++) mx=fmaxf(mx,scs[k]);
    float a[8]; float s=0;
#pragma unroll
    for(int k=0;k<8;k++){ a[k]=expf(scs[k]-mx); s+=a[k]; }
    float inv=1.0f/s;
    float na=0,nb=0,de=0;
#pragma unroll
    for(int k=0;k<8;k++){
      float lam = 2.0f/(1.0f+y2sk[k]); float w=a[k]*inv;
      na+=w*lam*HSa[k]; nb+=w*lam*HSb[k]; de+=w*(lam-1.0f);
    }
    de = fmaxf(fabsf(de),EPSF);
    na/=de; nb/=de;
    float vsq=wred(na*na+nb*nb); float nv=sqrtf(vsq+1e-15f);
    float tt=tan_c(0.5f*atanf(nv)); float f=tt/nv;
    float ha=f*na, hb=f*nb;
    float hn=sqrtf(f*f*vsq+1e-15f);
    float gl=atanf(hn)/hn;
    LS[i0]=gl*ha; LS[i1]=gl*hb;
  }
  { // e attention
    float mx=sce[0];
#pragma unroll
    for(int k=1;k<8;k++) mx=fmaxf(mx,sce[k]);
    float a[8]; float s=0;
#pragma unroll
    for(int k=0;k<8;k++){ a[k]=expf(sce[k]-mx); s+=a[k]; }
    float inv=1.0f/s;
    float ha=0,hb=0;
#pragma unroll
    for(int k=0;k<8;k++){ float w=a[k]*inv; ha+=w*HEa[k]; hb+=w*HEb[k]; }
    LE[i0]=ha; LE[i1]=hb;
  }
  { // c_1
    float de=fmaxf(fabsf(ds1),EPSF);
    float na=v1a/de, nb=v1b/de;
    float vsq=wred(na*na+nb*nb); float nv=sqrtf(vsq+1e-15f);
    float tt=tanhf(0.5f*atanh_c(nv)); float f=fminf(tt,PMX)/nv;
    C1o[i0]=f*na; C1o[i1]=f*nb;
    if(l==0) c1n2[n]=f*f*vsq;
  }
  { // c_2
    float de=fmaxf(fabsf(ds2),EPSF);
    float na=v2a/de, nb=v2b/de;
    float vsq=wred(na*na+nb*nb); float nv=sqrtf(vsq+1e-15f);
    float tt=tan_c(0.5f*atanf(nv)); float f=tt/nv;
    C2o[i0]=f*na; C2o[i1]=f*nb;
    if(l==0) c2n2[n]=f*f*vsq;
  }
  C3o[i0]=v3a; C3o[i1]=v3b;
}

// ---------------- kernel 6: final epilogue (phase C3) ----------------
__global__ __launch_bounds__(256) void k_final(
  const float* __restrict__ iou1, const float* __restrict__ iou2,
  const float* __restrict__ iou3, float* __restrict__ ws,
  float* __restrict__ out)
{
  const float* YP = ws; const float* YS = ws+3*NHS; const float* YE = ws+6*NHS;
  const float* C1v = ws+27*NHS; const float* C2v = ws+28*NHS; const float* C3v = ws+29*NHS;
  const float* c1n2 = ws+30*NHS+32768; const float* c2n2 = ws+30*NHS+40960;
  int n = blockIdx.x*4 + (threadIdx.x>>6);
  int l = threadIdx.x&63;
  size_t b384 = (size_t)n*384 + l;
  size_t b128 = (size_t)n*HD + l;
  // ================= Poincare =================
  {
    float Y[6], I[6];
#pragma unroll
    for(int r=0;r<6;r++){ Y[r]=YP[b384+64*r]; I[r]=iou1[b384+64*r]; }
    float sy=0,si=0,sx=0;
#pragma unroll
    for(int r=0;r<6;r++){ sy+=Y[r]*Y[r]; si+=I[r]*I[r]; sx+=I[r]*Y[r]; }
    sy=wred(sy); si=wred(si); sx=wred(sx);
    float nY=sqrtf(sy+1e-15f);
    float te=tanhf(nY); float fE=fminf(te,PMX)/nY;
    float y2=fE*fE*sy, x2=si, xy=fE*sx;
    float aa=1.0f+2.0f*xy+y2, bb=1.0f-x2;
    float dd=safeden(1.0f+2.0f*xy+x2*y2);
    float nio[6];
#pragma unroll
    for(int r=0;r<6;r++) nio[r]=(aa*I[r]+bb*fE*Y[r])/dd;
    float nsq=(aa*aa*x2+2.0f*aa*bb*xy+bb*bb*y2)/(dd*dd);
    { float nn=sqrtf(nsq+1e-15f);
      if(nn>PMX){ float sc=PMX/nn; for(int r=0;r<6;r++) nio[r]*=sc; } }
    float ci=wred(nio[0]*nio[0]+nio[1]*nio[1]); float ni=sqrtf(ci+1e-15f); float gi=atanh_c(ni)/ni;
    float ip0=sigm(gi*nio[0]), ip1=sigm(gi*nio[1]);
    float co=wred(nio[2]*nio[2]+nio[3]*nio[3]); float no=sqrtf(co+1e-15f); float go=atanh_c(no)/no;
    float op0=sigm(go*nio[2]), op1=sigm(go*nio[3]);
    float cu=wred(nio[4]*nio[4]+nio[5]*nio[5]); float nu=sqrtf(cu+1e-15f); float gu=atanh_c(nu)/nu;
    float up0=tanhf(gu*nio[4]), up1=tanhf(gu*nio[5]);
    float usq=wred(up0*up0+up1*up1); float nx=sqrtf(usq+1e-15f);
    float wv0=ip0*up0, wv1=ip1*up1;
    float wsq=wred(wv0*wv0+wv1*wv1); float nwx=sqrtf(wsq+1e-15f);
    float tP=tanhf(nwx/nx*atanh_c(nx)); float fP=fminf(tP,PMX)/nwx;
    float P0=fP*wv0, P1=fP*wv1; float p2=fP*fP*wsq;
    float ca=C1v[b128], cb=C1v[b128+64];
    float y2c=c1n2[n];
    float xyc=wred(P0*ca+P1*cb);
    float a3=1.0f+2.0f*xyc+y2c, b3=1.0f-p2;
    float d3=safeden(1.0f+2.0f*xyc+p2*y2c);
    float nc0=(a3*P0+b3*ca)/d3, nc1_=(a3*P1+b3*cb)/d3;
    float ncsq=(a3*a3*p2+2.0f*a3*b3*xyc+b3*b3*y2c)/(d3*d3);
    { float nn=sqrtf(ncsq+1e-15f);
      if(nn>PMX){ float sc=PMX/nn; nc0*=sc; nc1_*=sc; ncsq*=sc*sc; } }
    float nl=sqrtf(ncsq+1e-15f);
    float gL=atanh_c(nl)/nl;
    float T0=tanhf(gL*nc0), T1=tanhf(gL*nc1_);
    float tsq=wred(T0*T0+T1*T1); float nT=sqrtf(tsq+1e-15f);
    float wo0=op0*T0, wo1=op1*T1;
    float osq=wred(wo0*wo0+wo1*wo1); float nwo=sqrtf(osq+1e-15f);
    float tH=tanhf(nwo/nT*atanh_c(nT)); float fH=fminf(tH,PMX)/nwo;
    out[0*NHS + b128]=fH*wo0; out[0*NHS + b128+64]=fH*wo1;
    out[1*NHS + b128]=nc0;    out[1*NHS + b128+64]=nc1_;
  }
  // ================= Sphere =================
  {
    float Y[6], I[6];
#pragma unroll
    for(int r=0;r<6;r++){ Y[r]=YS[b384+64*r]; I[r]=iou2[b384+64*r]; }
    float sy=0,si=0,sx=0;
#pragma unroll
    for(int r=0;r<6;r++){ sy+=Y[r]*Y[r]; si+=I[r]*I[r]; sx+=I[r]*Y[r]; }
    sy=wred(sy); si=wred(si); sx=wred(sx);
    float nY=sqrtf(sy+1e-15f);
    float te=tan_c(nY); float fE=te/nY;
    float y2=fE*fE*sy, x2=si, xy=fE*sx;
    float aa=1.0f-2.0f*xy-y2, bb=1.0f+x2;
    float dd=safeden(1.0f-2.0f*xy+x2*y2);
    float nio[6];
#pragma unroll
    for(int r=0;r<6;r++) nio[r]=(aa*I[r]+bb*fE*Y[r])/dd;
    float ci=wred(nio[0]*nio[0]+nio[1]*nio[1]); float ni=sqrtf(ci+1e-15f); float gi=atanf(ni)/ni;
    float ip0=sigm(gi*nio[0]), ip1=sigm(gi*nio[1]);
    float co=wred(nio[2]*nio[2]+nio[3]*nio[3]); float no=sqrtf(co+1e-15f); float go=atanf(no)/no;
    float op0=sigm(go*nio[2]), op1=sigm(go*nio[3]);
    float cu=wred(nio[4]*nio[4]+nio[5]*nio[5]); float nu=sqrtf(cu+1e-15f); float gu=atanf(nu)/nu;
    float up0=tanhf(gu*nio[4]), up1=tanhf(gu*nio[5]);
    float usq=wred(up0*up0+up1*up1); float nx=sqrtf(usq+1e-15f);
    float wv0=ip0*up0, wv1=ip1*up1;
    float wsq=wred(wv0*wv0+wv1*wv1); float nwx=sqrtf(wsq+1e-15f);
    float tP=tan_c(nwx/nx*atanf(nx)); float fP=tP/nwx;
    float P0=fP*wv0, P1=fP*wv1; float p2=fP*fP*wsq;
    float ca=C2v[b128], cb=C2v[b128+64];
    float y2c=c2n2[n];
    float xyc=wred(P0*ca+P1*cb);
    float a3=1.0f-2.0f*xyc-y2c, b3=1.0f+p2;
    float d3=safeden(1.0f-2.0f*xyc+p2*y2c);
    float nc0=(a3*P0+b3*ca)/d3, nc1_=(a3*P1+b3*cb)/d3;
    float ncsq=(a3*a3*p2+2.0f*a3*b3*xyc+b3*b3*y2c)/(d3*d3);
    float nl=sqrtf(ncsq+1e-15f);
    float gL=atanf(nl)/nl;
    float T0=tanhf(gL*nc0), T1=tanhf(gL*nc1_);
    float tsq=wred(T0*T0+T1*T1); float nT=sqrtf(tsq+1e-15f);
    float wo0=op0*T0, wo1=op1*T1;
    float osq=wred(wo0*wo0+wo1*wo1); float nwo=sqrtf(osq+1e-15f);
    float tH=tan_c(nwo/nT*atanf(nT)); float fH=tH/nwo;
    out[2*NHS + b128]=fH*wo0; out[2*NHS + b128+64]=fH*wo1;
    out[3*NHS + b128]=nc0;    out[3*NHS + b128+64]=nc1_;
  }
  // ================= Euclid =================
  {
    float Y[6], I[6];
#pragma unroll
    for(int r=0;r<6;r++){ Y[r]=YE[b384+64*r]; I[r]=iou3[b384+64*r]; }
    float n0=I[0]+Y[0], n1=I[1]+Y[1];
    float n2=I[2]+Y[2], n3=I[3]+Y[3];
    float n4=I[4]+Y[4], n5=I[5]+Y[5];
    float ie0=sigm(n0), ie1=sigm(n1);
    float oe0=sigm(n2), oe1=sigm(n3);
    float ue0=tanhf(n4), ue1=tanhf(n5);
    float ca=C3v[b128], cb=C3v[b128+64];
    float nc0=ie0*ue0+ca, nc1_=ie1*ue1+cb;
    out[4*NHS + b128]=oe0*tanhf(nc0); out[4*NHS + b128+64]=oe1*tanhf(nc1_);
    out[5*NHS + b128]=nc0;            out[5*NHS + b128+64]=nc1_;
  }
}

extern "C" void kernel_launch(void* const* d_in, const int* in_sizes, int n_in,
                              void* d_out, int out_size, void* d_ws, size_t ws_size,
                              hipStream_t stream)
{
  const float* x     = (const float*)d_in[0];
  const float* h1    = (const float*)d_in[1];
  const float* c1    = (const float*)d_in[2];
  const float* h2    = (const float*)d_in[3];
  const float* c2    = (const float*)d_in[4];
  const float* h3    = (const float*)d_in[5];
  const float* c3    = (const float*)d_in[6];
  const float* del_t = (const float*)d_in[7];
  const float* iou1  = (const float*)d_in[8];
  const float* iou2  = (const float*)d_in[9];
  const float* iou3  = (const float*)d_in[10];
  const float* Wq_w  = (const float*)d_in[11];
  const float* Wq_b  = (const float*)d_in[12];
  const float* Wc_w  = (const float*)d_in[13];
  const float* Wc_b  = (const float*)d_in[14];
  const float* Uf_w  = (const float*)d_in[15];
  const float* Uf_b  = (const float*)d_in[16];
  const float* Up_w  = (const float*)d_in[17];
  const float* Up_b  = (const float*)d_in[18];
  const float* Uiou_w= (const float*)d_in[19];
  const float* Uiou_b= (const float*)d_in[20];
  const float* dsc   = (const float*)d_in[21];
  const int*   nbr   = (const int*)d_in[22];
  float* out = (float*)d_out;
  float* ws  = (float*)d_ws;

  k_pre<<<2048,256,0,stream>>>(x,h1,h2,c1,c2,ws);

  JobTab A{};
  // in, W, b, out, col0, pitch, post
  A.j[0]  = { ws+0*NHS, Wq_w, Wq_b, ws+15*NHS, 0, 128, P_EXP_P };      // XP
  A.j[1]  = { ws+1*NHS, Wq_w, Wq_b, ws+16*NHS, 0, 128, P_EXP_S };      // XS
  A.j[2]  = { x,        Wq_w, Wq_b, ws+17*NHS, 0, 128, P_ID };         // XE
  A.j[3]  = { ws+2*NHS, Up_w, Up_b, ws+6*NHS,  0, 128, P_SIG_LOG_P };  // S1
  A.j[4]  = { ws+3*NHS, Up_w, Up_b, ws+7*NHS,  0, 128, P_SIG_LOG_S };  // S2
  A.j[5]  = { h3,       Up_w, Up_b, ws+8*NHS,  0, 128, P_SIG };        // S3
  A.j[6]  = { ws+2*NHS, Uf_w, Uf_b, ws+9*NHS,  0, 128, P_LOGSIG_P };   // F1
  A.j[7]  = { ws+3*NHS, Uf_w, Uf_b, ws+10*NHS, 0, 128, P_LOGSIG_S };   // F2
  A.j[8]  = { h3,       Uf_w, Uf_b, ws+11*NHS, 0, 128, P_SIG };        // F3
  A.j[9]  = { ws+4*NHS, Wc_w, Wc_b, ws+12*NHS, 0, 128, P_TANH_EXP_P }; // CS1
  A.j[10] = { ws+5*NHS, Wc_w, Wc_b, ws+13*NHS, 0, 128, P_TANH_EXP_S }; // CS2
  A.j[11] = { c3,       Wc_w, Wc_b, ws+14*NHS, 0, 128, P_TANH };       // CS3
  k_gemm<<<dim3(256,12),256,0,stream>>>(A);

  k_phaseB<<<2048,256,0,stream>>>(h1,h2,h3,c1,c2,c3,del_t,dsc,ws);
  k_attn<<<2048,256,0,stream>>>(nbr,ws);

  JobTab B{};
  for(int ct=0; ct<3; ct++){
    B.j[0*3+ct] = { ws+24*NHS, Uiou_w, Uiou_b, ws+0*NHS, 128*ct, 384, P_ID }; // YP
    B.j[1*3+ct] = { ws+25*NHS, Uiou_w, Uiou_b, ws+3*NHS, 128*ct, 384, P_ID }; // YS
    B.j[2*3+ct] = { ws+26*NHS, Uiou_w, Uiou_b, ws+6*NHS, 128*ct, 384, P_ID }; // YE
  }
  k_gemm<<<dim3(256,9),256,0,stream>>>(B);

  k_final<<<2048,256,0,stream>>>(iou1,iou2,iou3,ws,out);
}

// Round 3
// 315.305 us; speedup vs baseline: 1.2621x; 1.2621x over previous
//
#include <hip/hip_runtime.h>
#include <math.h>

#define HD 128
#define NNODE 8192
#define KNBR 8
#define NHS ((size_t)NNODE*(size_t)HD)

#define EPSF 1e-6f
#define PMX 0.9999f
#define ATHC (1.0f-1e-5f)
#define TANC 1.47079f

// ---------- fast hardware math ----------
static __device__ __forceinline__ float frcp(float x){ return __builtin_amdgcn_rcpf(x); }
static __device__ __forceinline__ float fdiv(float a,float b){ return a*__builtin_amdgcn_rcpf(b); }
static __device__ __forceinline__ float fsqrt(float x){ return __builtin_amdgcn_sqrtf(x); }
static __device__ __forceinline__ float fexp(float x){ return __builtin_amdgcn_exp2f(x*1.4426950408889634f); }
static __device__ __forceinline__ float flog(float x){ return __builtin_amdgcn_logf(x)*0.6931471805599453f; }
static __device__ __forceinline__ float ftanh(float x){
  float ax = fabsf(x);
  float e = fexp(-2.0f*ax);
  float t = (1.0f-e)*frcp(1.0f+e);
  return copysignf(t,x);
}
static __device__ __forceinline__ float fatanh(float x){ // clamped
  x = fminf(fmaxf(x,-ATHC),ATHC);
  return 0.5f*flog((1.0f+x)*frcp(1.0f-x));
}
static __device__ __forceinline__ float fatan(float x){
  float ax = fabsf(x);
  bool inv = ax > 1.0f;
  float t = inv ? frcp(ax) : ax;
  float t2 = t*t;
  float p = -0.0117212f;
  p = p*t2 + 0.05265332f;
  p = p*t2 - 0.11643287f;
  p = p*t2 + 0.19354346f;
  p = p*t2 - 0.33262347f;
  p = p*t2 + 0.99997726f;
  float r = t*p;
  r = inv ? 1.5707963267948966f - r : r;
  return copysignf(r,x);
}
static __device__ __forceinline__ float ftan(float x){ // pre-clamped to |x|<=TANC
  x = fminf(fmaxf(x,-TANC),TANC);
  float r = x*0.15915494309189535f; // 1/(2pi) -> revolutions
  float s = __builtin_amdgcn_sinf(r);
  float c = __builtin_amdgcn_cosf(r);
  return s*frcp(c);
}
static __device__ __forceinline__ float sigm(float x){ return frcp(1.0f+fexp(-x)); }
static __device__ __forceinline__ float safeden(float d){
  return d>=0.0f ? fmaxf(d,EPSF) : fminf(d,-EPSF);
}

static __device__ __forceinline__ float wred(float v){
#pragma unroll
  for(int m=32;m;m>>=1) v += __shfl_xor(v,m,64);
  return v;
}
static __device__ __forceinline__ float hred(float v){
#pragma unroll
  for(int m=16;m;m>>=1) v += __shfl_xor(v,m,64);
  return v;
}

// ---------------- workspace layout (units of NHS floats) ----------------
// 0..5  : XPre1, XPre2, LH1, LH2, LC1, LC2        (dead after GEMM-A)
// 6..11 : S1,S2,S3,F1,F2,F3
// 12..14: CS1,CS2,CS3
// 15..17: XP,XS,XE
// 18..20: H1P,H1S,H1E
// 21..23: V1,V2,V3
// 24..26: LP,LS,LE
// 27..29: c_1,c_2,c_3
// YP/YS/YE overlay 0..8
// scalars at 30*NHS: y2p(+0), y2s(+8192), d1(+16384), d2(+24576), c1n2(+32768), c2n2(+40960)

__global__ __launch_bounds__(256) void k_pre(
    const float* __restrict__ x, const float* __restrict__ h1,
    const float* __restrict__ h2, const float* __restrict__ c1,
    const float* __restrict__ c2, float* __restrict__ ws)
{
  float* XP1 = ws + 0*NHS; float* XP2 = ws + 1*NHS;
  float* LH1 = ws + 2*NHS; float* LH2 = ws + 3*NHS;
  float* LC1 = ws + 4*NHS; float* LC2 = ws + 5*NHS;
  int row = blockIdx.x*4 + (threadIdx.x>>6);
  int l = threadIdx.x & 63;
  size_t i0 = (size_t)row*HD + l, i1 = i0 + 64;
  float xa=x[i0], xb=x[i1];
  float h1a=h1[i0], h1b=h1[i1];
  float h2a=h2[i0], h2b=h2[i1];
  float c1a=c1[i0], c1b=c1[i1];
  float c2a=c2[i0], c2b=c2[i1];
  float xsq = wred(xa*xa+xb*xb);
  float h1sq = wred(h1a*h1a+h1b*h1b);
  float h2sq = wred(h2a*h2a+h2b*h2b);
  float c1sq = wred(c1a*c1a+c1b*c1b);
  float c2sq = wred(c2a*c2a+c2b*c2b);
  float nx = fsqrt(xsq+1e-15f);
  {
    float t = ftanh(nx);
    float f = fminf(t,PMX)*frcp(nx);
    float ny = fsqrt(f*f*xsq + 1e-15f);
    float g = fatanh(ny)*frcp(ny) * f;
    XP1[i0]=g*xa; XP1[i1]=g*xb;
  }
  {
    float t = ftan(nx);
    float f = t*frcp(nx);
    float ny = fsqrt(f*f*xsq + 1e-15f);
    float g = fatan(ny)*frcp(ny) * f;
    XP2[i0]=g*xa; XP2[i1]=g*xb;
  }
  { float n=fsqrt(h1sq+1e-15f); float g=fatanh(n)*frcp(n); LH1[i0]=g*h1a; LH1[i1]=g*h1b; }
  { float n=fsqrt(h2sq+1e-15f); float g=fatan(n)*frcp(n);  LH2[i0]=g*h2a; LH2[i1]=g*h2b; }
  { float n=fsqrt(c1sq+1e-15f); float g=fatanh(n)*frcp(n); LC1[i0]=g*c1a; LC1[i1]=g*c1b; }
  { float n=fsqrt(c2sq+1e-15f); float g=fatan(n)*frcp(n);  LC2[i0]=g*c2a; LC2[i1]=g*c2b; }
}

// ---------------- generic tiled f32 GEMM: out = post(in @ W^T + b) ----------------
enum { P_ID=0, P_EXP_P, P_EXP_S, P_SIG, P_TANH, P_SIG_LOG_P, P_SIG_LOG_S,
       P_LOGSIG_P, P_LOGSIG_S, P_TANH_EXP_P, P_TANH_EXP_S };

struct Job { const float* in; const float* W; const float* b; float* out;
             int col0; int pitch; int post; };
struct JobTab { Job j[12]; };

__global__ __launch_bounds__(256) void k_gemm(JobTab tab){
  Job jb = tab.j[blockIdx.y];
  __shared__ float Wt[64*128];
  __shared__ float Un[32*132];
  const int t = threadIdx.x;
  const int r0 = blockIdx.x*32;
#pragma unroll
  for(int rep=0;rep<4;rep++){
    int idx = t + 256*rep;
    int r = idx>>5, i4 = (idx&31)<<2;
    const float4 v = *(const float4*)(jb.in + (size_t)(r0+r)*HD + i4);
    *(float4*)&Un[r*132 + i4] = v;
  }
  float acc[4][4];
#pragma unroll
  for(int a=0;a<4;a++)
#pragma unroll
    for(int b=0;b<4;b++) acc[a][b]=0.0f;
  const int oo = t&31, gg = t>>5;
  const int o4 = oo*4, r4 = gg*4;
  const float* Wb = jb.W + (size_t)jb.col0*HD;
  for(int h=0;h<2;h++){
    __syncthreads();
#pragma unroll
    for(int rep=0;rep<8;rep++){
      int idx = t + 256*rep;
      int i4q = idx&15, o = idx>>4;
      int il = i4q*4;
      const float4 v = *(const float4*)(Wb + (size_t)o*HD + 64*h + il);
      int oc = o ^ ((i4q&7)<<2);
      Wt[(il+0)*128 + oc] = v.x;
      Wt[(il+1)*128 + oc] = v.y;
      Wt[(il+2)*128 + oc] = v.z;
      Wt[(il+3)*128 + oc] = v.w;
    }
    __syncthreads();
    const int ib = 64*h;
#pragma unroll 2
    for(int i4=0;i4<64;i4+=4){
      const int sw = o4 ^ (((i4>>2)&7)<<2);
      const float4 w0 = *(const float4*)&Wt[(i4+0)*128 + sw];
      const float4 w1 = *(const float4*)&Wt[(i4+1)*128 + sw];
      const float4 w2 = *(const float4*)&Wt[(i4+2)*128 + sw];
      const float4 w3 = *(const float4*)&Wt[(i4+3)*128 + sw];
      const float4 u0 = *(const float4*)&Un[(r4+0)*132 + ib+i4];
      const float4 u1 = *(const float4*)&Un[(r4+1)*132 + ib+i4];
      const float4 u2 = *(const float4*)&Un[(r4+2)*132 + ib+i4];
      const float4 u3 = *(const float4*)&Un[(r4+3)*132 + ib+i4];
#define ACC4(A,U) \
      acc[A][0]+=U.x*w0.x+U.y*w1.x+U.z*w2.x+U.w*w3.x; \
      acc[A][1]+=U.x*w0.y+U.y*w1.y+U.z*w2.y+U.w*w3.y; \
      acc[A][2]+=U.x*w0.z+U.y*w1.z+U.z*w2.z+U.w*w3.z; \
      acc[A][3]+=U.x*w0.w+U.y*w1.w+U.z*w2.w+U.w*w3.w;
      ACC4(0,u0) ACC4(1,u1) ACC4(2,u2) ACC4(3,u3)
#undef ACC4
    }
  }
  float bar[4];
  { const float4 bv = *(const float4*)(jb.b + jb.col0 + o4);
    bar[0]=bv.x; bar[1]=bv.y; bar[2]=bv.z; bar[3]=bv.w; }
  float v[4][4];
#pragma unroll
  for(int a=0;a<4;a++)
#pragma unroll
    for(int b=0;b<4;b++) v[a][b] = acc[a][b] + bar[b];
  float nraw[4];
#pragma unroll
  for(int a=0;a<4;a++){
    float s = v[a][0]*v[a][0]+v[a][1]*v[a][1]+v[a][2]*v[a][2]+v[a][3]*v[a][3];
    nraw[a] = hred(s);
  }
  switch(jb.post){
    case P_ID: break;
    case P_EXP_P:
#pragma unroll
      for(int a=0;a<4;a++){
        float n=fsqrt(nraw[a]+1e-15f); float tt=ftanh(n); float f=fminf(tt,PMX)*frcp(n);
        for(int b=0;b<4;b++) v[a][b]*=f;
      } break;
    case P_EXP_S:
#pragma unroll
      for(int a=0;a<4;a++){
        float n=fsqrt(nraw[a]+1e-15f); float f=ftan(n)*frcp(n);
        for(int b=0;b<4;b++) v[a][b]*=f;
      } break;
    case P_SIG:
#pragma unroll
      for(int a=0;a<4;a++) for(int b=0;b<4;b++) v[a][b]=sigm(v[a][b]);
      break;
    case P_TANH:
#pragma unroll
      for(int a=0;a<4;a++) for(int b=0;b<4;b++) v[a][b]=ftanh(v[a][b]);
      break;
    case P_SIG_LOG_P:
#pragma unroll
      for(int a=0;a<4;a++){
        float n=fsqrt(nraw[a]+1e-15f); float tt=ftanh(n); float f=fminf(tt,PMX)*frcp(n);
        float z[4];
        for(int b=0;b<4;b++) z[b]=sigm(f*v[a][b]);
        float zr=hred(z[0]*z[0]+z[1]*z[1]+z[2]*z[2]+z[3]*z[3]);
        float zn=fsqrt(zr+1e-15f);
        float g=fatanh(zn)*frcp(zn);
        for(int b=0;b<4;b++) v[a][b]=g*z[b];
      } break;
    case P_SIG_LOG_S:
#pragma unroll
      for(int a=0;a<4;a++){
        float n=fsqrt(nraw[a]+1e-15f); float f=ftan(n)*frcp(n);
        float z[4];
        for(int b=0;b<4;b++) z[b]=sigm(f*v[a][b]);
        float zr=hred(z[0]*z[0]+z[1]*z[1]+z[2]*z[2]+z[3]*z[3]);
        float zn=fsqrt(zr+1e-15f);
        float g=fatan(zn)*frcp(zn);
        for(int b=0;b<4;b++) v[a][b]=g*z[b];
      } break;
    case P_LOGSIG_P:
#pragma unroll
      for(int a=0;a<4;a++){
        float n=fsqrt(nraw[a]+1e-15f); float tt=ftanh(n); float f=fminf(tt,PMX)*frcp(n);
        float ny=fsqrt(f*f*nraw[a]+1e-15f);
        float g=fatanh(ny)*frcp(ny)*f;
        for(int b=0;b<4;b++) v[a][b]=sigm(g*v[a][b]);
      } break;
    case P_LOGSIG_S:
#pragma unroll
      for(int a=0;a<4;a++){
        float n=fsqrt(nraw[a]+1e-15f); float f=ftan(n)*frcp(n);
        float ny=fsqrt(f*f*nraw[a]+1e-15f);
        float g=fatan(ny)*frcp(ny)*f;
        for(int b=0;b<4;b++) v[a][b]=sigm(g*v[a][b]);
      } break;
    case P_TANH_EXP_P:
#pragma unroll
      for(int a=0;a<4;a++){
        float n=fsqrt(nraw[a]+1e-15f); float tt=ftanh(n); float f=fminf(tt,PMX)*frcp(n);
        float ny=fsqrt(f*f*nraw[a]+1e-15f);
        float g=fatanh(ny)*frcp(ny)*f;
        float T[4];
        for(int b=0;b<4;b++) T[b]=ftanh(g*v[a][b]);
        float Tr=hred(T[0]*T[0]+T[1]*T[1]+T[2]*T[2]+T[3]*T[3]);
        float Tn=fsqrt(Tr+1e-15f);
        float t2=ftanh(Tn); float f2=fminf(t2,PMX)*frcp(Tn);
        for(int b=0;b<4;b++) v[a][b]=f2*T[b];
      } break;
    case P_TANH_EXP_S:
#pragma unroll
      for(int a=0;a<4;a++){
        float n=fsqrt(nraw[a]+1e-15f); float f=ftan(n)*frcp(n);
        float ny=fsqrt(f*f*nraw[a]+1e-15f);
        float g=fatan(ny)*frcp(ny)*f;
        float T[4];
        for(int b=0;b<4;b++) T[b]=ftanh(g*v[a][b]);
        float Tr=hred(T[0]*T[0]+T[1]*T[1]+T[2]*T[2]+T[3]*T[3]);
        float Tn=fsqrt(Tr+1e-15f);
        float f2=ftan(Tn)*frcp(Tn);
        for(int b=0;b<4;b++) v[a][b]=f2*T[b];
      } break;
  }
#pragma unroll
  for(int a=0;a<4;a++){
    float4 ov = make_float4(v[a][0],v[a][1],v[a][2],v[a][3]);
    *(float4*)(jb.out + (size_t)(r0+r4+a)*jb.pitch + jb.col0 + o4) = ov;
  }
}

// ---------------- kernel 3: per-unique-node elementwise (phase B) ----------------
__global__ __launch_bounds__(256) void k_phaseB(
  const float* __restrict__ h1,const float* __restrict__ h2,const float* __restrict__ h3,
  const float* __restrict__ c1,const float* __restrict__ c2,const float* __restrict__ c3,
  const float* __restrict__ del_t, const float* __restrict__ dsc,
  float* __restrict__ ws)
{
  const float* S1 = ws+6*NHS;  const float* S2 = ws+7*NHS;  const float* S3 = ws+8*NHS;
  const float* F1 = ws+9*NHS;  const float* F2 = ws+10*NHS; const float* F3 = ws+11*NHS;
  const float* Q1 = ws+12*NHS; const float* Q2 = ws+13*NHS; const float* Q3 = ws+14*NHS;
  float* H1P = ws+18*NHS; float* H1S = ws+19*NHS; float* H1E = ws+20*NHS;
  float* V1 = ws+21*NHS;  float* V2 = ws+22*NHS;  float* V3 = ws+23*NHS;
  float* y2p = ws+30*NHS; float* y2s = y2p+8192; float* d1 = y2p+16384; float* d2 = y2p+24576;

  int j = blockIdx.x*4 + (threadIdx.x>>6);
  int l = threadIdx.x&63;
  size_t i0 = (size_t)j*HD+l, i1 = i0+64;
  float h1a=h1[i0],h1b=h1[i1], h2a=h2[i0],h2b=h2[i1], h3a=h3[i0],h3b=h3[i1];
  float c1a=c1[i0],c1b=c1[i1], c2a=c2[i0],c2b=c2[i1], c3a=c3[i0],c3b=c3[i1];
  float s1a=S1[i0],s1b=S1[i1], s2a=S2[i0],s2b=S2[i1], s3a=S3[i0],s3b=S3[i1];
  float f1a=F1[i0],f1b=F1[i1], f2a=F2[i0],f2b=F2[i1], f3a=F3[i0],f3b=F3[i1];
  float q1a=Q1[i0],q1b=Q1[i1], q2a=Q2[i0],q2b=Q2[i1], q3a=Q3[i0],q3b=Q3[i1];
  float g = fdiv(dsc[0], del_t[j]+1.0f);

  float h1sq = wred(h1a*h1a+h1b*h1b); float n1 = fsqrt(h1sq+1e-15f);
  float h2sq = wred(h2a*h2a+h2b*h2b); float n2 = fsqrt(h2sq+1e-15f);
  float h3sq = wred(h3a*h3a+h3b*h3b); float n3 = fsqrt(h3sq+1e-15f);
  float w1a=s1a*h1a, w1b=s1b*h1b;
  float w2a=s2a*h2a, w2b=s2b*h2b;
  float w3a=s3a*h3a, w3b=s3b*h3b;
  float w1sq = wred(w1a*w1a+w1b*w1b); float nw1 = fsqrt(w1sq+1e-15f);
  float w2sq = wred(w2a*w2a+w2b*w2b); float nw2 = fsqrt(w2sq+1e-15f);
  float w3sq = wred(w3a*w3a+w3b*w3b); float nw3 = fsqrt(w3sq+1e-15f);

  // ---- h_1p
  float t1 = ftanh(nw1*frcp(n1) * fatanh(n1));
  float fp1 = fminf(t1,PMX)*frcp(nw1); float np1 = fminf(t1,PMX);
  float nu2 = fatan(n2);
  float ne2 = fminf(ftanh(nu2),PMX);
  float t2 = ftanh(nw2*frcp(n2) * fatanh(ne2));
  float fp2 = fminf(t2,PMX)*frcp(nw2); float np2 = fminf(t2,PMX);
  float ne3 = fminf(ftanh(n3),PMX);
  float t3 = ftanh(nw3*frcp(n3) * fatanh(ne3));
  float fp3 = fminf(t3,PMX)*frcp(nw3); float np3 = fminf(t3,PMX);
  {
    float lamA = 2.0f*frcp(1.0f-np1*np1), lamB = 2.0f*frcp(1.0f-np2*np2), lamC = 2.0f*frcp(1.0f-np3*np3);
    float dn = frcp(fmaxf(fabsf(lamA+lamB+lamC-3.0f), EPSF));
    float va = (lamA*fp1*w1a + lamB*fp2*w2a + lamC*fp3*w3a)*dn;
    float vb = (lamA*fp1*w1b + lamB*fp2*w2b + lamC*fp3*w3b)*dn;
    float vsq = wred(va*va+vb*vb); float nv = fsqrt(vsq+1e-15f);
    float tt = ftanh(0.5f*fatanh(nv)); float ff = 3.0f*fminf(tt,PMX)*frcp(nv);
    H1P[i0]=ff*va; H1P[i1]=ff*vb;
    if(l==0) y2p[j] = ff*ff*vsq;
  }
  // ---- h_1s
  float t2s, fs2;
  {
    float nx1s = ftan(fatanh(n1));
    float t1s = ftanh(nw1*frcp(n1) * fatanh(nx1s));
    float fs1 = fminf(t1s,PMX)*frcp(nw1); float ns1 = fminf(t1s,PMX);
    t2s = ftan(nw2*frcp(n2) * fatan(n2));
    fs2 = t2s*frcp(nw2);
    float nx3s = ftan(n3);
    float t3s = ftan(nw3*frcp(n3) * fatan(nx3s));
    float fs3 = t3s*frcp(nw3);
    float lA = 2.0f*frcp(1.0f-ns1*ns1), lB = 2.0f*frcp(1.0f-t2s*t2s), lC = 2.0f*frcp(1.0f-t3s*t3s);
    float dns = frcp(fmaxf(fabsf(lA+lB+lC-3.0f), EPSF));
    float vsa = (lA*fs1*w1a + lB*fs2*w2a + lC*fs3*w3a)*dns;
    float vsb = (lA*fs1*w1b + lB*fs2*w2b + lC*fs3*w3b)*dns;
    float vssq = wred(vsa*vsa+vsb*vsb); float nvs = fsqrt(vssq+1e-15f);
    float tts = ftan(0.5f*fatan(nvs)); float ffs = 3.0f*tts*frcp(nvs);
    H1S[i0]=ffs*vsa; H1S[i1]=ffs*vsb;
    if(l==0) y2s[j] = ffs*ffs*vssq;
  }
  // ---- h_1e
  {
    float ne1 = fsqrt(fp1*fp1*w1sq + 1e-15f);
    float ge1 = fatanh(ne1)*frcp(ne1);
    float n2s_ = fsqrt(fs2*fs2*w2sq + 1e-15f);
    float ge2 = fatan(n2s_)*frcp(n2s_);
    H1E[i0] = ge1*fp1*w1a + ge2*fs2*w2a + s3a*h3a;
    H1E[i1] = ge1*fp1*w1b + ge2*fs2*w2b + s3b*h3b;
  }
  float ng = fsqrt(g*g+1e-15f);
  // ---- Poincare cell
  {
    float q1sq = wred(q1a*q1a+q1b*q1b);
    float c1rs = wred(c1a*c1a+c1b*c1b);
    float dq1 = wred(q1a*c1a+q1b*c1b);
    float xy = -dq1;
    float aa = 1.0f+2.0f*xy+c1rs, bb = 1.0f-q1sq;
    float dd = frcp(safeden(1.0f+2.0f*xy+q1sq*c1rs));
    float m1a = (aa*(-q1a)+bb*c1a)*dd, m1b = (aa*(-q1b)+bb*c1b)*dd;
    float m1sq = (aa*aa*q1sq + 2.0f*aa*bb*xy + bb*bb*c1rs)*dd*dd;
    float mdq = (-aa*q1sq + bb*dq1)*dd;
    { float nm = fsqrt(m1sq+1e-15f);
      if(nm>PMX){ float sc=PMX*frcp(nm); m1a*=sc; m1b*=sc; m1sq*=sc*sc; mdq*=sc; } }
    float nwg = fsqrt(g*g*q1sq+1e-15f);
    float tg = ftanh(nwg*frcp(ng) * fatanh(ng));
    float fX = fminf(tg,PMX)*frcp(nwg) * g;
    float X2sq = fX*fX*q1sq;
    float xy2 = fX*mdq;
    float a2 = 1.0f+2.0f*xy2+X2sq, b2 = 1.0f-m1sq;
    float d2d = frcp(safeden(1.0f+2.0f*xy2+m1sq*X2sq));
    float ka = (a2*m1a + b2*fX*q1a)*d2d, kb = (a2*m1b + b2*fX*q1b)*d2d;
    float ksq = (a2*a2*m1sq + 2.0f*a2*b2*xy2 + b2*b2*X2sq)*d2d*d2d;
    { float nk0 = fsqrt(ksq+1e-15f);
      if(nk0>PMX){ float sc=PMX*frcp(nk0); ka*=sc; kb*=sc; ksq*=sc*sc; } }
    float nk = fsqrt(ksq+1e-15f);
    float wfa = f1a*ka, wfb = f1b*kb;
    float wfsq = wred(wfa*wfa+wfb*wfb); float nwf = fsqrt(wfsq+1e-15f);
    float tu = ftanh(nwf*frcp(nk) * fatanh(nk));
    float fu = fminf(tu,PMX)*frcp(nwf);
    float u1sq = fu*fu*wfsq;
    float lam = 2.0f*frcp(1.0f-u1sq);
    V1[i0]=lam*fu*wfa; V1[i1]=lam*fu*wfb;
    if(l==0) d1[j]=lam-1.0f;
  }
  // ---- Sphere cell
  {
    float q2sq = wred(q2a*q2a+q2b*q2b);
    float c2rs = wred(c2a*c2a+c2b*c2b);
    float dq2 = wred(q2a*c2a+q2b*c2b);
    float xy = -dq2;
    float aa = 1.0f-2.0f*xy-c2rs, bb = 1.0f+q2sq;
    float dd = frcp(safeden(1.0f-2.0f*xy+q2sq*c2rs));
    float ma = (aa*(-q2a)+bb*c2a)*dd, mb = (aa*(-q2b)+bb*c2b)*dd;
    float msq = (aa*aa*q2sq + 2.0f*aa*bb*xy + bb*bb*c2rs)*dd*dd;
    float mdq = (-aa*q2sq + bb*dq2)*dd;
    float nwg = fsqrt(g*g*q2sq+1e-15f);
    float tg = ftan(nwg*frcp(ng) * fatan(ng));
    float fX = tg*frcp(nwg) * g;
    float X2sq = fX*fX*q2sq;
    float xy2 = fX*mdq;
    float a2 = 1.0f-2.0f*xy2-X2sq, b2 = 1.0f+msq;
    float d2d = frcp(safeden(1.0f-2.0f*xy2+msq*X2sq));
    float ka = (a2*ma + b2*fX*q2a)*d2d, kb = (a2*mb + b2*fX*q2b)*d2d;
    float ksq = (a2*a2*msq + 2.0f*a2*b2*xy2 + b2*b2*X2sq)*d2d*d2d;
    float nk = fsqrt(ksq+1e-15f);
    float wfa = f2a*ka, wfb = f2b*kb;
    float wfsq = wred(wfa*wfa+wfb*wfb); float nwf = fsqrt(wfsq+1e-15f);
    float tu = ftan(nwf*frcp(nk) * fatan(nk));
    float fu = tu*frcp(nwf);
    float u2sq = fu*fu*wfsq;
    float lam = 2.0f*frcp(1.0f+u2sq);
    V2[i0]=lam*fu*wfa; V2[i1]=lam*fu*wfb;
    if(l==0) d2[j]=lam-1.0f;
  }
  // ---- Euclid cell
  {
    float kea = c3a + q3a*(g-1.0f), keb = c3b + q3b*(g-1.0f);
    V3[i0]=f3a*kea; V3[i1]=f3b*keb;
  }
}

// ---------------- kernel 4: attention + K-reductions ----------------
__global__ __launch_bounds__(256) void k_attn(
  const int* __restrict__ nbr, float* __restrict__ ws)
{
  const float* XP = ws+15*NHS; const float* XS = ws+16*NHS; const float* XE = ws+17*NHS;
  const float* H1P = ws+18*NHS; const float* H1S = ws+19*NHS; const float* H1E = ws+20*NHS;
  const float* V1 = ws+21*NHS; const float* V2 = ws+22*NHS; const float* V3 = ws+23*NHS;
  float* LP = ws+24*NHS; float* LS = ws+25*NHS; float* LE = ws+26*NHS;
  float* C1o = ws+27*NHS; float* C2o = ws+28*NHS; float* C3o = ws+29*NHS;
  const float* y2p = ws+30*NHS; const float* y2s = y2p+8192;
  const float* d1 = y2p+16384; const float* d2 = y2p+24576;
  float* c1n2 = (float*)(y2p+32768); float* c2n2 = (float*)(y2p+40960);

  int n = blockIdx.x*4 + (threadIdx.x>>6);
  int l = threadIdx.x&63;
  size_t i0 = (size_t)n*HD+l, i1 = i0+64;
  float XPa=XP[i0], XPb=XP[i1];
  float XSa=XS[i0], XSb=XS[i1];
  float XEa=XE[i0], XEb=XE[i1];
  float x2p = wred(XPa*XPa+XPb*XPb);
  float x2s = wred(XSa*XSa+XSb*XSb);
  float HPa[8],HPb[8],HSa[8],HSb[8],HEa[8],HEb[8],y2pk[8],y2sk[8];
  float scp[8],scs[8],sce[8];
  float v1a=0,v1b=0,v2a=0,v2b=0,v3a=0,v3b=0,ds1=0,ds2=0;
  const float rs = 0.08838834764831845f;
#pragma unroll
  for(int k=0;k<8;k++){
    int j = nbr[n*KNBR+k];
    size_t j0 = (size_t)j*HD+l, j1 = j0+64;
    HPa[k]=H1P[j0]; HPb[k]=H1P[j1];
    HSa[k]=H1S[j0]; HSb[k]=H1S[j1];
    HEa[k]=H1E[j0]; HEb[k]=H1E[j1];
    y2pk[k]=y2p[j]; y2sk[k]=y2s[j];
    v1a+=V1[j0]; v1b+=V1[j1];
    v2a+=V2[j0]; v2b+=V2[j1];
    v3a+=V3[j0]; v3b+=V3[j1];
    ds1+=d1[j]; ds2+=d2[j];
    float dp = wred(XPa*HPa[k]+XPb*HPb[k]);
    {
      float xy=-dp, y2=y2pk[k];
      float aa=1.0f+2.0f*xy+y2, bb=1.0f-x2p;
      float dd=frcp(safeden(1.0f+2.0f*xy+x2p*y2));
      float nsq=(aa*aa*x2p+2.0f*aa*bb*xy+bb*bb*y2)*dd*dd;
      float nn=fminf(fsqrt(nsq+1e-15f),PMX);
      scp[k] = -2.0f*fatanh(nn);
    }
    float dsv = wred(XSa*HSa[k]+XSb*HSb[k]);
    {
      float xy=-dsv, y2=y2sk[k];
      float aa=1.0f-2.0f*xy-y2, bb=1.0f+x2s;
      float dd=frcp(safeden(1.0f-2.0f*xy+x2s*y2));
      float nsq=(aa*aa*x2s+2.0f*aa*bb*xy+bb*bb*y2)*dd*dd;
      float nn=fsqrt(nsq+1e-15f);
      scs[k] = -2.0f*fatan(nn);
    }
    sce[k] = wred(XEa*HEa[k]+XEb*HEb[k])*rs;
  }
  { // p attention + wmid
    float mx=scp[0];
#pragma unroll
    for(int k=1;k<8;k++) mx=fmaxf(mx,scp[k]);
    float a[8]; float s=0;
#pragma unroll
    for(int k=0;k<8;k++){ a[k]=fexp(scp[k]-mx); s+=a[k]; }
    float inv=frcp(s);
    float na=0,nb=0,de=0;
#pragma unroll
    for(int k=0;k<8;k++){
      float lam = 2.0f*frcp(1.0f-y2pk[k]); float w=a[k]*inv;
      na+=w*lam*HPa[k]; nb+=w*lam*HPb[k]; de+=w*(lam-1.0f);
    }
    de = frcp(fmaxf(fabsf(de),EPSF));
    na*=de; nb*=de;
    float vsq=wred(na*na+nb*nb); float nv=fsqrt(vsq+1e-15f);
    float tt=ftanh(0.5f*fatanh(nv)); float f=fminf(tt,PMX)*frcp(nv);
    float ha=f*na, hb=f*nb;
    float hn=fsqrt(f*f*vsq+1e-15f);
    float gl=fatanh(hn)*frcp(hn);
    LP[i0]=gl*ha; LP[i1]=gl*hb;
  }
  { // s attention + wmid
    float mx=scs[0];
#pragma unroll
    for(int k=1;k<8;k++) mx=fmaxf(mx,scs[k]);
    float a[8]; float s=0;
#pragma unroll
    for(int k=0;k<8;k++){ a[k]=fexp(scs[k]-mx); s+=a[k]; }
    float inv=frcp(s);
    float na=0,nb=0,de=0;
#pragma unroll
    for(int k=0;k<8;k++){
      float lam = 2.0f*frcp(1.0f+y2sk[k]); float w=a[k]*inv;
      na+=w*lam*HSa[k]; nb+=w*lam*HSb[k]; de+=w*(lam-1.0f);
    }
    de = frcp(fmaxf(fabsf(de),EPSF));
    na*=de; nb*=de;
    float vsq=wred(na*na+nb*nb); float nv=fsqrt(vsq+1e-15f);
    float tt=ftan(0.5f*fatan(nv)); float f=tt*frcp(nv);
    float ha=f*na, hb=f*nb;
    float hn=fsqrt(f*f*vsq+1e-15f);
    float gl=fatan(hn)*frcp(hn);
    LS[i0]=gl*ha; LS[i1]=gl*hb;
  }
  { // e attention
    float mx=sce[0];
#pragma unroll
    for(int k=1;k<8;k++) mx=fmaxf(mx,sce[k]);
    float a[8]; float s=0;
#pragma unroll
    for(int k=0;k<8;k++){ a[k]=fexp(sce[k]-mx); s+=a[k]; }
    float inv=frcp(s);
    float ha=0,hb=0;
#pragma unroll
    for(int k=0;k<8;k++){ float w=a[k]*inv; ha+=w*HEa[k]; hb+=w*HEb[k]; }
    LE[i0]=ha; LE[i1]=hb;
  }
  { // c_1
    float de=frcp(fmaxf(fabsf(ds1),EPSF));
    float na=v1a*de, nb=v1b*de;
    float vsq=wred(na*na+nb*nb); float nv=fsqrt(vsq+1e-15f);
    float tt=ftanh(0.5f*fatanh(nv)); float f=fminf(tt,PMX)*frcp(nv);
    C1o[i0]=f*na; C1o[i1]=f*nb;
    if(l==0) c1n2[n]=f*f*vsq;
  }
  { // c_2
    float de=frcp(fmaxf(fabsf(ds2),EPSF));
    float na=v2a*de, nb=v2b*de;
    float vsq=wred(na*na+nb*nb); float nv=fsqrt(vsq+1e-15f);
    float tt=ftan(0.5f*fatan(nv)); float f=tt*frcp(nv);
    C2o[i0]=f*na; C2o[i1]=f*nb;
    if(l==0) c2n2[n]=f*f*vsq;
  }
  C3o[i0]=v3a; C3o[i1]=v3b;
}

// ---------------- kernel 6: final epilogue ----------------
__global__ __launch_bounds__(256) void k_final(
  const float* __restrict__ iou1, const float* __restrict__ iou2,
  const float* __restrict__ iou3, float* __restrict__ ws,
  float* __restrict__ out)
{
  const float* YP = ws; const float* YS = ws+3*NHS; const float* YE = ws+6*NHS;
  const float* C1v = ws+27*NHS; const float* C2v = ws+28*NHS; const float* C3v = ws+29*NHS;
  const float* c1n2 = ws+30*NHS+32768; const float* c2n2 = ws+30*NHS+40960;
  int n = blockIdx.x*4 + (threadIdx.x>>6);
  int l = threadIdx.x&63;
  size_t b384 = (size_t)n*384 + l;
  size_t b128 = (size_t)n*HD + l;
  // ================= Poincare =================
  {
    float Y[6], I[6];
#pragma unroll
    for(int r=0;r<6;r++){ Y[r]=YP[b384+64*r]; I[r]=iou1[b384+64*r]; }
    float sy=0,si=0,sx=0;
#pragma unroll
    for(int r=0;r<6;r++){ sy+=Y[r]*Y[r]; si+=I[r]*I[r]; sx+=I[r]*Y[r]; }
    sy=wred(sy); si=wred(si); sx=wred(sx);
    float nY=fsqrt(sy+1e-15f);
    float te=ftanh(nY); float fE=fminf(te,PMX)*frcp(nY);
    float y2=fE*fE*sy, x2=si, xy=fE*sx;
    float aa=1.0f+2.0f*xy+y2, bb=1.0f-x2;
    float dd=frcp(safeden(1.0f+2.0f*xy+x2*y2));
    float nio[6];
#pragma unroll
    for(int r=0;r<6;r++) nio[r]=(aa*I[r]+bb*fE*Y[r])*dd;
    float nsq=(aa*aa*x2+2.0f*aa*bb*xy+bb*bb*y2)*dd*dd;
    { float nn=fsqrt(nsq+1e-15f);
      if(nn>PMX){ float sc=PMX*frcp(nn); for(int r=0;r<6;r++) nio[r]*=sc; } }
    float ci=wred(nio[0]*nio[0]+nio[1]*nio[1]); float ni=fsqrt(ci+1e-15f); float gi=fatanh(ni)*frcp(ni);
    float ip0=sigm(gi*nio[0]), ip1=sigm(gi*nio[1]);
    float co=wred(nio[2]*nio[2]+nio[3]*nio[3]); float no=fsqrt(co+1e-15f); float go=fatanh(no)*frcp(no);
    float op0=sigm(go*nio[2]), op1=sigm(go*nio[3]);
    float cu=wred(nio[4]*nio[4]+nio[5]*nio[5]); float nu=fsqrt(cu+1e-15f); float gu=fatanh(nu)*frcp(nu);
    float up0=ftanh(gu*nio[4]), up1=ftanh(gu*nio[5]);
    float usq=wred(up0*up0+up1*up1); float nx=fsqrt(usq+1e-15f);
    float wv0=ip0*up0, wv1=ip1*up1;
    float wsq=wred(wv0*wv0+wv1*wv1); float nwx=fsqrt(wsq+1e-15f);
    float tP=ftanh(nwx*frcp(nx)*fatanh(nx)); float fP=fminf(tP,PMX)*frcp(nwx);
    float P0=fP*wv0, P1=fP*wv1; float p2=fP*fP*wsq;
    float ca=C1v[b128], cb=C1v[b128+64];
    float y2c=c1n2[n];
    float xyc=wred(P0*ca+P1*cb);
    float a3=1.0f+2.0f*xyc+y2c, b3=1.0f-p2;
    float d3=frcp(safeden(1.0f+2.0f*xyc+p2*y2c));
    float nc0=(a3*P0+b3*ca)*d3, nc1_=(a3*P1+b3*cb)*d3;
    float ncsq=(a3*a3*p2+2.0f*a3*b3*xyc+b3*b3*y2c)*d3*d3;
    { float nn=fsqrt(ncsq+1e-15f);
      if(nn>PMX){ float sc=PMX*frcp(nn); nc0*=sc; nc1_*=sc; ncsq*=sc*sc; } }
    float nl=fsqrt(ncsq+1e-15f);
    float gL=fatanh(nl)*frcp(nl);
    float T0=ftanh(gL*nc0), T1=ftanh(gL*nc1_);
    float tsq=wred(T0*T0+T1*T1); float nT=fsqrt(tsq+1e-15f);
    float wo0=op0*T0, wo1=op1*T1;
    float osq=wred(wo0*wo0+wo1*wo1); float nwo=fsqrt(osq+1e-15f);
    float tH=ftanh(nwo*frcp(nT)*fatanh(nT)); float fH=fminf(tH,PMX)*frcp(nwo);
    out[0*NHS + b128]=fH*wo0; out[0*NHS + b128+64]=fH*wo1;
    out[1*NHS + b128]=nc0;    out[1*NHS + b128+64]=nc1_;
  }
  // ================= Sphere =================
  {
    float Y[6], I[6];
#pragma unroll
    for(int r=0;r<6;r++){ Y[r]=YS[b384+64*r]; I[r]=iou2[b384+64*r]; }
    float sy=0,si=0,sx=0;
#pragma unroll
    for(int r=0;r<6;r++){ sy+=Y[r]*Y[r]; si+=I[r]*I[r]; sx+=I[r]*Y[r]; }
    sy=wred(sy); si=wred(si); sx=wred(sx);
    float nY=fsqrt(sy+1e-15f);
    float te=ftan(nY); float fE=te*frcp(nY);
    float y2=fE*fE*sy, x2=si, xy=fE*sx;
    float aa=1.0f-2.0f*xy-y2, bb=1.0f+x2;
    float dd=frcp(safeden(1.0f-2.0f*xy+x2*y2));
    float nio[6];
#pragma unroll
    for(int r=0;r<6;r++) nio[r]=(aa*I[r]+bb*fE*Y[r])*dd;
    float ci=wred(nio[0]*nio[0]+nio[1]*nio[1]); float ni=fsqrt(ci+1e-15f); float gi=fatan(ni)*frcp(ni);
    float ip0=sigm(gi*nio[0]), ip1=sigm(gi*nio[1]);
    float co=wred(nio[2]*nio[2]+nio[3]*nio[3]); float no=fsqrt(co+1e-15f); float go=fatan(no)*frcp(no);
    float op0=sigm(go*nio[2]), op1=sigm(go*nio[3]);
    float cu=wred(nio[4]*nio[4]+nio[5]*nio[5]); float nu=fsqrt(cu+1e-15f); float gu=fatan(nu)*frcp(nu);
    float up0=ftanh(gu*nio[4]), up1=ftanh(gu*nio[5]);
    float usq=wred(up0*up0+up1*up1); float nx=fsqrt(usq+1e-15f);
    float wv0=ip0*up0, wv1=ip1*up1;
    float wsq=wred(wv0*wv0+wv1*wv1); float nwx=fsqrt(wsq+1e-15f);
    float tP=ftan(nwx*frcp(nx)*fatan(nx)); float fP=tP*frcp(nwx);
    float P0=fP*wv0, P1=fP*wv1; float p2=fP*fP*wsq;
    float ca=C2v[b128], cb=C2v[b128+64];
    float y2c=c2n2[n];
    float xyc=wred(P0*ca+P1*cb);
    float a3=1.0f-2.0f*xyc-y2c, b3=1.0f+p2;
    float d3=frcp(safeden(1.0f-2.0f*xyc+p2*y2c));
    float nc0=(a3*P0+b3*ca)*d3, nc1_=(a3*P1+b3*cb)*d3;
    float ncsq=(a3*a3*p2+2.0f*a3*b3*xyc+b3*b3*y2c)*d3*d3;
    float nl=fsqrt(ncsq+1e-15f);
    float gL=fatan(nl)*frcp(nl);
    float T0=ftanh(gL*nc0), T1=ftanh(gL*nc1_);
    float tsq=wred(T0*T0+T1*T1); float nT=fsqrt(tsq+1e-15f);
    float wo0=op0*T0, wo1=op1*T1;
    float osq=wred(wo0*wo0+wo1*wo1); float nwo=fsqrt(osq+1e-15f);
    float tH=ftan(nwo*frcp(nT)*fatan(nT)); float fH=tH*frcp(nwo);
    out[2*NHS + b128]=fH*wo0; out[2*NHS + b128+64]=fH*wo1;
    out[3*NHS + b128]=nc0;    out[3*NHS + b128+64]=nc1_;
  }
  // ================= Euclid =================
  {
    float Y[6], I[6];
#pragma unroll
    for(int r=0;r<6;r++){ Y[r]=YE[b384+64*r]; I[r]=iou3[b384+64*r]; }
    float n0=I[0]+Y[0], n1=I[1]+Y[1];
    float n2=I[2]+Y[2], n3=I[3]+Y[3];
    float n4=I[4]+Y[4], n5=I[5]+Y[5];
    float ie0=sigm(n0), ie1=sigm(n1);
    float oe0=sigm(n2), oe1=sigm(n3);
    float ue0=ftanh(n4), ue1=ftanh(n5);
    float ca=C3v[b128], cb=C3v[b128+64];
    float nc0=ie0*ue0+ca, nc1_=ie1*ue1+cb;
    out[4*NHS + b128]=oe0*ftanh(nc0); out[4*NHS + b128+64]=oe1*ftanh(nc1_);
    out[5*NHS + b128]=nc0;            out[5*NHS + b128+64]=nc1_;
  }
}

extern "C" void kernel_launch(void* const* d_in, const int* in_sizes, int n_in,
                              void* d_out, int out_size, void* d_ws, size_t ws_size,
                              hipStream_t stream)
{
  const float* x     = (const float*)d_in[0];
  const float* h1    = (const float*)d_in[1];
  const float* c1    = (const float*)d_in[2];
  const float* h2    = (const float*)d_in[3];
  const float* c2    = (const float*)d_in[4];
  const float* h3    = (const float*)d_in[5];
  const float* c3    = (const float*)d_in[6];
  const float* del_t = (const float*)d_in[7];
  const float* iou1  = (const float*)d_in[8];
  const float* iou2  = (const float*)d_in[9];
  const float* iou3  = (const float*)d_in[10];
  const float* Wq_w  = (const float*)d_in[11];
  const float* Wq_b  = (const float*)d_in[12];
  const float* Wc_w  = (const float*)d_in[13];
  const float* Wc_b  = (const float*)d_in[14];
  const float* Uf_w  = (const float*)d_in[15];
  const float* Uf_b  = (const float*)d_in[16];
  const float* Up_w  = (const float*)d_in[17];
  const float* Up_b  = (const float*)d_in[18];
  const float* Uiou_w= (const float*)d_in[19];
  const float* Uiou_b= (const float*)d_in[20];
  const float* dsc   = (const float*)d_in[21];
  const int*   nbr   = (const int*)d_in[22];
  float* out = (float*)d_out;
  float* ws  = (float*)d_ws;

  k_pre<<<2048,256,0,stream>>>(x,h1,h2,c1,c2,ws);

  JobTab A{};
  A.j[0]  = { ws+0*NHS, Wq_w, Wq_b, ws+15*NHS, 0, 128, P_EXP_P };
  A.j[1]  = { ws+1*NHS, Wq_w, Wq_b, ws+16*NHS, 0, 128, P_EXP_S };
  A.j[2]  = { x,        Wq_w, Wq_b, ws+17*NHS, 0, 128, P_ID };
  A.j[3]  = { ws+2*NHS, Up_w, Up_b, ws+6*NHS,  0, 128, P_SIG_LOG_P };
  A.j[4]  = { ws+3*NHS, Up_w, Up_b, ws+7*NHS,  0, 128, P_SIG_LOG_S };
  A.j[5]  = { h3,       Up_w, Up_b, ws+8*NHS,  0, 128, P_SIG };
  A.j[6]  = { ws+2*NHS, Uf_w, Uf_b, ws+9*NHS,  0, 128, P_LOGSIG_P };
  A.j[7]  = { ws+3*NHS, Uf_w, Uf_b, ws+10*NHS, 0, 128, P_LOGSIG_S };
  A.j[8]  = { h3,       Uf_w, Uf_b, ws+11*NHS, 0, 128, P_SIG };
  A.j[9]  = { ws+4*NHS, Wc_w, Wc_b, ws+12*NHS, 0, 128, P_TANH_EXP_P };
  A.j[10] = { ws+5*NHS, Wc_w, Wc_b, ws+13*NHS, 0, 128, P_TANH_EXP_S };
  A.j[11] = { c3,       Wc_w, Wc_b, ws+14*NHS, 0, 128, P_TANH };
  k_gemm<<<dim3(256,12),256,0,stream>>>(A);

  k_phaseB<<<2048,256,0,stream>>>(h1,h2,h3,c1,c2,c3,del_t,dsc,ws);
  k_attn<<<2048,256,0,stream>>>(nbr,ws);

  JobTab B{};
  for(int ct=0; ct<3; ct++){
    B.j[0*3+ct] = { ws+24*NHS, Uiou_w, Uiou_b, ws+0*NHS, 128*ct, 384, P_ID };
    B.j[1*3+ct] = { ws+25*NHS, Uiou_w, Uiou_b, ws+3*NHS, 128*ct, 384, P_ID };
    B.j[2*3+ct] = { ws+26*NHS, Uiou_w, Uiou_b, ws+6*NHS, 128*ct, 384, P_ID };
  }
  k_gemm<<<dim3(256,9),256,0,stream>>>(B);

  k_final<<<2048,256,0,stream>>>(iou1,iou2,iou3,ws,out);
}